// Round 2
// baseline (21305.501 us; speedup 1.0000x reference)
//
#include <hip/hip_runtime.h>
#include <hip/hip_bf16.h>
#include <math.h>

// Problem constants
#define B_   32
#define S_   512
#define V_   30000
#define E_   300
#define H_   200
#define NH_  4
#define ENC_ 400
#define G4_  800     // 4*H
#define NEGV  (-1e9f)
#define SCALE_ 1000.0f

// ---- workspace layout (float offsets) ---- total 33,272,384 floats = ~127 MiB
#define OF_WTF   0ull          // W_hh_f^T  [200][800]
#define OF_WTB   160000ull     // W_hh_b^T  [200][800]
#define OF_QVEC  320000ull     // q_state @ W_q  [400]
#define OF_WKQ   320448ull     // wkq [400][4]
#define OF_THETA 322048ull     // scores [B][4][512]  (region reused by HX/ARR during LSTM)
#define OF_MU    387584ull     // mu     [B][4][512]
#define OF_HP    453120ull     // hp [B][4][400]
#define OF_LEN   504320ull     // lengths (int) [32]
#define OF_XWF   504384ull     // xW forward  [B*S][800]
#define OF_XWB   13611584ull   // xW backward (natural s order) [B*S][800]
#define OF_HF    26718784ull   // h_f [B*S][200]
#define OF_HB    29995584ull   // h_b [B*S][200]
// LSTM exchange buffers: live only during k_lstm4, then dead. Alias onto THETA
// (written by k_scores strictly after k_lstm4 completes).
#define OF_HX    322048ull     // hx [64 chains][2][200] = 25600 floats
#define OF_ARR   347648ull     // arrive counters [64] uint

// -------- lengths from mask (dtype auto-detect: u8 / i32 / i64) --------
__global__ void k_lengths(const void* __restrict__ mask, int* __restrict__ lengths) {
  int b = blockIdx.x, lane = threadIdx.x;
  const unsigned char* mb = (const unsigned char*)mask;
  int mode;
  if (mb[1] != 0) mode = 0;
  else if (((const int*)mask)[1] != 0) mode = 1;
  else mode = 2;
  int cnt = 0;
  for (int s = lane; s < S_; s += 64) {
    int v;
    if (mode == 0)      v = mb[b*S_ + s] ? 1 : 0;
    else if (mode == 1) v = ((const int*)mask)[b*S_ + s] ? 1 : 0;
    else                v = ((const long long*)mask)[b*S_ + s] ? 1 : 0;
    cnt += v;
  }
  for (int off = 32; off; off >>= 1) cnt += __shfl_xor(cnt, off);
  if (lane == 0) lengths[b] = cnt;
}

// -------- transpose W_hh [800,200] -> WT [200,800] (both dirs) --------
__global__ void k_transpose(const float* __restrict__ Wf, const float* __restrict__ Wb,
                            float* __restrict__ WTf, float* __restrict__ WTb) {
  __shared__ float tile[64][65];
  int bi = blockIdx.x;
  int m = bi / 52, rem = bi % 52;
  int tr = rem / 4, tc = rem % 4;
  const float* src = m ? Wb : Wf;
  float* dst = m ? WTb : WTf;
  int t = threadIdx.x;
  int lx = t & 63, ly = t >> 6;
  int r0 = tr*64, k0 = tc*64;
  #pragma unroll
  for (int i = 0; i < 16; ++i) {
    int r = r0 + ly*16 + i, k = k0 + lx;
    if (r < G4_ && k < H_) tile[lx][ly*16+i] = src[(size_t)r*H_ + k];
  }
  __syncthreads();
  #pragma unroll
  for (int i = 0; i < 16; ++i) {
    int k = k0 + ly*16 + i, r = r0 + lx;
    if (r < G4_ && k < H_) dst[(size_t)k*G4_ + r] = tile[ly*16+i][lx];
  }
}

// -------- qvec = q_state @ W_q --------
__global__ void k_qvec(const float* __restrict__ qs, const float* __restrict__ Wq,
                       float* __restrict__ qvec) {
  __shared__ float qsl[ENC_];
  int t = threadIdx.x;
  if (t < ENC_) qsl[t] = qs[t];
  __syncthreads();
  if (t < ENC_) {
    float acc = 0.f;
    for (int i = 0; i < ENC_; ++i) acc += qsl[i] * Wq[(size_t)i*ENC_ + t];
    qvec[t] = acc;
  }
}

// -------- wkq[e][head] --------
__global__ void k_wkq(const float* __restrict__ Wk, const float* __restrict__ qvec,
                      float* __restrict__ wkq) {
  int t = threadIdx.x;
  int e = blockIdx.x*64 + (t >> 2);
  int head = t & 3;
  if (e < ENC_) {
    float acc = 0.f;
    const float* row = Wk + (size_t)e*ENC_ + head*100;
    const float* qv  = qvec + head*100;
    for (int d = 0; d < 100; ++d) acc += row[d]*qv[d];
    wkq[e*4 + head] = acc;
  }
}

// -------- input projections GEMM (unchanged from passing round) --------
__global__ __launch_bounds__(256) void k_gemm_in(
    const int* __restrict__ x, const float* __restrict__ emb,
    const float* __restrict__ wf, const float* __restrict__ wb,
    const float* __restrict__ bf, const float* __restrict__ bb,
    float* __restrict__ xWf, float* __restrict__ xWb)
{
  __shared__ int xid[128];
  __shared__ __align__(16) float sA[16][128];
  __shared__ __align__(16) float sB[16][64];
  const int t = threadIdx.x;
  const int row0 = blockIdx.x * 128;
  const int col0 = blockIdx.y * 64;
  if (t < 128) xid[t] = x[row0 + t];
  __syncthreads();
  float acc[8][4];
  #pragma unroll
  for (int i = 0; i < 8; ++i)
    #pragma unroll
    for (int j = 0; j < 4; ++j) acc[i][j] = 0.f;
  const int y = t >> 4, xq = t & 15;
  const int rl = t >> 1, half = t & 1;
  const int cb = t & 63, kq = t >> 6;
  const int colg_b = col0 + cb;
  const float* wsrc = (colg_b < 800) ? (wf + (size_t)colg_b*300)
                                     : (wb + (size_t)(colg_b-800)*300);
  const float* asrc = emb + (size_t)xid[rl]*300;
  for (int kc = 0; kc < 19; ++kc) {
    const int k0 = kc*16;
    {
      const int kb = k0 + half*8;
      const float* src = asrc + kb;
      if (kb + 7 < 300) {
        float4 a  = *(const float4*)(src);
        float4 b4 = *(const float4*)(src+4);
        sA[half*8+0][rl]=a.x;  sA[half*8+1][rl]=a.y;  sA[half*8+2][rl]=a.z;  sA[half*8+3][rl]=a.w;
        sA[half*8+4][rl]=b4.x; sA[half*8+5][rl]=b4.y; sA[half*8+6][rl]=b4.z; sA[half*8+7][rl]=b4.w;
      } else {
        #pragma unroll
        for (int i = 0; i < 8; ++i) sA[half*8+i][rl] = (kb+i < 300) ? src[i] : 0.f;
      }
    }
    {
      const int kb = k0 + kq*4;
      if (kb + 3 < 300) {
        float4 w4 = *(const float4*)(wsrc + kb);
        sB[kq*4+0][cb]=w4.x; sB[kq*4+1][cb]=w4.y; sB[kq*4+2][cb]=w4.z; sB[kq*4+3][cb]=w4.w;
      } else {
        #pragma unroll
        for (int i = 0; i < 4; ++i) sB[kq*4+i][cb] = (kb+i < 300) ? wsrc[kb+i] : 0.f;
      }
    }
    __syncthreads();
    #pragma unroll
    for (int k = 0; k < 16; ++k) {
      float4 a0 = *(const float4*)&sA[k][y*8];
      float4 a1 = *(const float4*)&sA[k][y*8+4];
      float4 b4 = *(const float4*)&sB[k][xq*4];
      float av[8] = {a0.x,a0.y,a0.z,a0.w,a1.x,a1.y,a1.z,a1.w};
      float bv[4] = {b4.x,b4.y,b4.z,b4.w};
      #pragma unroll
      for (int i = 0; i < 8; ++i)
        #pragma unroll
        for (int j = 0; j < 4; ++j) acc[i][j] += av[i]*bv[j];
    }
    __syncthreads();
  }
  const int colg = col0 + xq*4;
  const bool isF = (colg < 800);
  const int colo = isF ? colg : (colg - 800);
  float4 bias = isF ? *(const float4*)(bf + colo) : *(const float4*)(bb + colo);
  float* dst = isF ? xWf : xWb;
  #pragma unroll
  for (int i = 0; i < 8; ++i) {
    int row = row0 + y*8 + i;
    float4 o = {acc[i][0]+bias.x, acc[i][1]+bias.y, acc[i][2]+bias.z, acc[i][3]+bias.w};
    *(float4*)(dst + (size_t)row*800 + colo) = o;
  }
}

// -------- weight-stationary multi-WG LSTM --------
// 64 chains (dir,b) x 4 WGs; WG g owns units [50g,50g+50) = 200 gate rows.
// Thread (wave ws = k-slice of 25, lane l = rows {l,64+l,128+l,192+l}) holds
// 100 W_hh weights in VGPRs (loaded once, coalesced from WT). Per step:
//   spin(arrive>=4*step) -> broadcast-load h k-slice -> 100 FMA ->
//   LDS part[8][256] reduce -> rsum[256] -> wave0 lanes<50: gates+elementwise,
//   publish h to hx[chain][(step+1)&1] + hout -> t0: release fetch_add.
// The spin doubles as the barrier protecting part[] reuse: waves 1-7 cannot
// re-enter part-writes for step+1 until own t0 (post-2nd-__syncthreads stage-b)
// has incremented. hx reads use relaxed ATOMIC loads: blocks the compiler from
// selecting s_load (scalar cache is not reliably invalidated by the acquire).
__global__ __launch_bounds__(512, 2) void k_lstm4(
    const float* __restrict__ xWf, const float* __restrict__ xWb,
    const float* __restrict__ WTf, const float* __restrict__ WTb,
    const int* __restrict__ lengths,
    float* __restrict__ h_f, float* __restrict__ h_b,
    float* __restrict__ hx, unsigned int* __restrict__ arrive)
{
  const int bid = blockIdx.x;
  // XCD swizzle: chain's 4 WGs share blockIdx%8 -> same XCD (heuristic).
  const int xcd = bid & 7, kk = bid >> 3;
  const int g = kk & 3;
  const int c = ((kk >> 2) << 3) | xcd;     // chain 0..63
  const int dir = c >> 5, b = c & 31;
  const float* __restrict__ xW = dir ? xWb : xWf;
  const float* __restrict__ WT = dir ? WTb : WTf;
  float* __restrict__ hout = dir ? h_b : h_f;
  const int len = lengths[b];
  const int t = threadIdx.x;
  const int ws = t >> 6, l = t & 63;

  __shared__ float part[8][256];
  __shared__ float rsum[256];

  // ---- one-time weight preload into VGPRs ----
  int rglob[4]; int rval[4];
  #pragma unroll
  for (int rr = 0; rr < 4; ++rr) {
    int r = l + 64*rr;                      // logical row = gate*50 + unit_local
    rval[rr] = (r < 200);
    int gate = r / 50, ul = r - gate*50;
    rglob[rr] = rval[rr] ? (gate*200 + 50*g + ul) : 0;
  }
  float wreg[4][25];
  #pragma unroll
  for (int j = 0; j < 25; ++j) {
    const float* wrow = WT + (size_t)(25*ws + j)*G4_;
    #pragma unroll
    for (int rr = 0; rr < 4; ++rr)
      wreg[rr][j] = rval[rr] ? wrow[rglob[rr]] : 0.f;
  }

  unsigned int* __restrict__ arr = arrive + c;
  float* __restrict__ hxc = hx + (size_t)c*2*H_;
  const int is50 = (t < 50);
  float cst = 0.f;

  for (int step = 0; step < len; ++step) {
    const int pos = dir ? (len-1-step) : step;
    // prefetch xW gate inputs for the elementwise lanes (independent of h)
    float xw_i=0.f, xw_f=0.f, xw_g=0.f, xw_o=0.f;
    if (is50) {
      const float* xr = xW + ((size_t)b*S_ + pos)*G4_ + 50*g + t;
      xw_i = xr[0]; xw_f = xr[200]; xw_g = xr[400]; xw_o = xr[600];
    }
    if (step) {
      const unsigned tgt = 4u*(unsigned)step;
      int guard = 0;
      while (__hip_atomic_load(arr, __ATOMIC_ACQUIRE, __HIP_MEMORY_SCOPE_AGENT) < tgt) {
        __builtin_amdgcn_s_sleep(1);
        if (++guard > (1<<28)) break;       // safety valve: wrong answer > hang
      }
    }
    // wave-uniform broadcast loads of this k-slice of h
    const float* hs = hxc + (size_t)(step & 1)*H_ + 25*ws;
    float acc0=0.f, acc1=0.f, acc2=0.f, acc3=0.f;
    #pragma unroll
    for (int j = 0; j < 25; ++j) {
      float hv = __hip_atomic_load(hs + j, __ATOMIC_RELAXED, __HIP_MEMORY_SCOPE_AGENT);
      acc0 += wreg[0][j]*hv; acc1 += wreg[1][j]*hv;
      acc2 += wreg[2][j]*hv; acc3 += wreg[3][j]*hv;
    }
    part[ws][l]       = acc0;
    part[ws][l + 64]  = acc1;
    part[ws][l + 128] = acc2;
    part[ws][l + 192] = acc3;
    __syncthreads();
    if (t < 256) {
      rsum[t] = ((part[0][t]+part[1][t])+(part[2][t]+part[3][t]))
              + ((part[4][t]+part[5][t])+(part[6][t]+part[7][t]));
    }
    __syncthreads();
    if (is50) {
      float gi = rsum[t]       + xw_i;
      float gf = rsum[t + 50]  + xw_f;
      float gg = rsum[t + 100] + xw_g;
      float go = rsum[t + 150] + xw_o;
      float ig = 1.f/(1.f+expf(-gi));
      float fg = 1.f/(1.f+expf(-gf));
      float og = 1.f/(1.f+expf(-go));
      cst = fg*cst + ig*tanhf(gg);
      float hn = og*tanhf(cst);
      hxc[(size_t)((step+1)&1)*H_ + 50*g + t] = hn;
      hout[((size_t)b*S_ + pos)*H_ + 50*g + t] = hn;
    }
    if (t == 0) {
      __hip_atomic_fetch_add(arr, 1u, __ATOMIC_RELEASE, __HIP_MEMORY_SCOPE_AGENT);
    }
  }
}

// -------- scores --------
__global__ __launch_bounds__(256) void k_scores(
    const float* __restrict__ hf, const float* __restrict__ hb,
    const float* __restrict__ wkq, const int* __restrict__ lengths,
    float* __restrict__ theta)
{
  int wid = blockIdx.x*4 + (threadIdx.x >> 6);
  int lane = threadIdx.x & 63;
  int b = wid >> 9, s = wid & 511;
  const float* hfr = hf + ((size_t)b*S_ + s)*H_;
  const float* hbr = hb + ((size_t)b*S_ + s)*H_;
  float a0=0.f, a1=0.f, a2=0.f, a3=0.f;
  for (int e = lane; e < ENC_; e += 64) {
    float hv = (e < H_) ? hfr[e] : hbr[e-H_];
    float4 w = *(const float4*)(wkq + e*4);
    a0 += hv*w.x; a1 += hv*w.y; a2 += hv*w.z; a3 += hv*w.w;
  }
  for (int off = 32; off; off >>= 1) {
    a0 += __shfl_xor(a0, off); a1 += __shfl_xor(a1, off);
    a2 += __shfl_xor(a2, off); a3 += __shfl_xor(a3, off);
  }
  if (lane == 0) {
    bool valid = s < lengths[b];
    size_t base = (size_t)b*2048 + s;
    theta[base       ] = valid ? SCALE_*a0 : NEGV;
    theta[base +  512] = valid ? SCALE_*a1 : NEGV;
    theta[base + 1024] = valid ? SCALE_*a2 : NEGV;
    theta[base + 1536] = valid ? SCALE_*a3 : NEGV;
  }
}

// -------- sparseMAP budget projection --------
__global__ void k_sparsemap(const float* __restrict__ theta, const int* __restrict__ lengths,
                            float* __restrict__ mu) {
  int pid = blockIdx.x;
  int lane = threadIdx.x;
  const float* th = theta + (size_t)pid*512;
  float v[8];
  #pragma unroll
  for (int i = 0; i < 8; ++i) v[i] = th[i*64 + lane];
  float kf = rintf(0.2f * (float)lengths[pid >> 2]);
  float mn = v[0], mx = v[0];
  #pragma unroll
  for (int i = 1; i < 8; ++i) { mn = fminf(mn, v[i]); mx = fmaxf(mx, v[i]); }
  for (int off = 32; off; off >>= 1) {
    mn = fminf(mn, __shfl_xor(mn, off)); mx = fmaxf(mx, __shfl_xor(mx, off));
  }
  float lo = mn - 1.f, hi = mx;
  for (int it = 0; it < 60; ++it) {
    float mid = 0.5f*(lo + hi);
    float s = 0.f;
    #pragma unroll
    for (int i = 0; i < 8; ++i) s += fminf(fmaxf(v[i]-mid, 0.f), 1.f);
    for (int off = 32; off; off >>= 1) s += __shfl_xor(s, off);
    bool big = s > kf;
    lo = big ? mid : lo;
    hi = big ? hi : mid;
  }
  float tau0 = 0.5f*(lo + hi);
  float fs = 0.f, nU = 0.f, nS = 0.f;
  #pragma unroll
  for (int i = 0; i < 8; ++i) {
    float m0 = v[i] - tau0;
    if (m0 >= 1.f) nU += 1.f;
    else if (m0 > 0.f) { fs += v[i]; nS += 1.f; }
  }
  for (int off = 32; off; off >>= 1) {
    fs += __shfl_xor(fs, off); nU += __shfl_xor(nU, off); nS += __shfl_xor(nS, off);
  }
  float tau = (fs + nU - kf) / fmaxf(nS, 1.f);
  tau = (nS > 0.f) ? tau : tau0;
  float* mo = mu + (size_t)pid*512;
  #pragma unroll
  for (int i = 0; i < 8; ++i) mo[i*64 + lane] = fminf(fmaxf(v[i]-tau, 0.f), 1.f);
}

// -------- hp[b,head,e] = sum_s mu * h --------
__global__ __launch_bounds__(512) void k_hp(
    const float* __restrict__ mu, const float* __restrict__ hf,
    const float* __restrict__ hb, float* __restrict__ hp)
{
  __shared__ float mul[512];
  int pid = blockIdx.x, b = pid >> 2;
  int t = threadIdx.x;
  mul[t] = mu[(size_t)pid*512 + t];
  __syncthreads();
  if (t < ENC_) {
    const float* hsrc = (t < H_) ? (hf + t) : (hb + (t - H_));
    float acc = 0.f;
    for (int s = 0; s < 512; ++s) {
      float m = mul[s];
      if (m != 0.f) acc += m * hsrc[((size_t)b*S_ + s)*H_];
    }
    hp[(size_t)pid*ENC_ + t] = acc;
  }
}

// -------- head --------
__global__ __launch_bounds__(512) void k_head(
    const float* __restrict__ hp, const float* __restrict__ Wv,
    const float* __restrict__ Wout, const float* __restrict__ Wh,
    const float* __restrict__ bh, float* __restrict__ out)
{
  __shared__ float hpl[1600];
  __shared__ float ppl[ENC_];
  __shared__ float ojl[ENC_];
  __shared__ float red[512];
  int b = blockIdx.x, t = threadIdx.x;
  for (int i = t; i < 1600; i += 512) hpl[i] = hp[(size_t)b*1600 + i];
  __syncthreads();
  if (t < ENC_) {
    int head = t / 100;
    float acc = 0.f;
    for (int e = 0; e < ENC_; ++e) acc += hpl[head*ENC_ + e] * Wv[(size_t)e*ENC_ + t];
    ppl[t] = acc;
  }
  __syncthreads();
  if (t < ENC_) {
    float acc = 0.f;
    for (int c = 0; c < ENC_; ++c) acc += ppl[c] * Wout[(size_t)c*ENC_ + t];
    ojl[t] = acc;
  }
  __syncthreads();
  red[t] = (t < ENC_) ? ojl[t]*Wh[t] : 0.f;
  __syncthreads();
  for (int sft = 256; sft; sft >>= 1) {
    if (t < sft) red[t] += red[t+sft];
    __syncthreads();
  }
  if (t == 0) out[b] = 1.f/(1.f + expf(-(red[0] + bh[0])));
}

// -------- z --------
__global__ void k_z(const float* __restrict__ mu, const int* __restrict__ lengths,
                    float* __restrict__ out) {
  int idx = blockIdx.x*256 + threadIdx.x;
  int b = idx >> 9, s = idx & 511;
  float zz = 0.f;
  if (s < lengths[b]) {
    size_t base = (size_t)b*2048 + s;
    zz = 0.25f*(mu[base] + mu[base+512] + mu[base+1024] + mu[base+1536]);
  }
  out[32 + idx] = zz;
}

extern "C" void kernel_launch(void* const* d_in, const int* in_sizes, int n_in,
                              void* d_out, int out_size, void* d_ws, size_t ws_size,
                              hipStream_t stream) {
  const int*   x    = (const int*)d_in[0];
  const void*  mask = d_in[1];
  const float* emb  = (const float*)d_in[2];
  const float* wihf = (const float*)d_in[3];
  const float* whhf = (const float*)d_in[4];
  const float* bf   = (const float*)d_in[5];
  const float* wihb = (const float*)d_in[6];
  const float* whhb = (const float*)d_in[7];
  const float* bb   = (const float*)d_in[8];
  const float* qs   = (const float*)d_in[9];
  const float* Wq   = (const float*)d_in[10];
  const float* Wk   = (const float*)d_in[11];
  const float* Wv   = (const float*)d_in[12];
  const float* Wout = (const float*)d_in[13];
  const float* Wh   = (const float*)d_in[14];
  const float* bh   = (const float*)d_in[15];
  float* out = (float*)d_out;
  float* W = (float*)d_ws;
  int* lengths = (int*)(W + OF_LEN);

  k_lengths<<<32, 64, 0, stream>>>(mask, lengths);
  k_transpose<<<104, 256, 0, stream>>>(whhf, whhb, W+OF_WTF, W+OF_WTB);
  k_qvec<<<1, 512, 0, stream>>>(qs, Wq, W+OF_QVEC);
  k_wkq<<<7, 256, 0, stream>>>(Wk, W+OF_QVEC, W+OF_WKQ);
  // zero LSTM exchange state (hx double-buffer + arrive counters)
  hipMemsetAsync(W+OF_HX, 0, (size_t)(64*2*H_)*sizeof(float) + 64*sizeof(unsigned), stream);
  k_gemm_in<<<dim3(128, 25), 256, 0, stream>>>(x, emb, wihf, wihb, bf, bb,
                                               W+OF_XWF, W+OF_XWB);
  k_lstm4<<<256, 512, 0, stream>>>(W+OF_XWF, W+OF_XWB, W+OF_WTF, W+OF_WTB,
                                   lengths, W+OF_HF, W+OF_HB,
                                   W+OF_HX, (unsigned int*)(W+OF_ARR));
  k_scores<<<4096, 256, 0, stream>>>(W+OF_HF, W+OF_HB, W+OF_WKQ, lengths, W+OF_THETA);
  k_sparsemap<<<128, 64, 0, stream>>>(W+OF_THETA, lengths, W+OF_MU);
  k_hp<<<128, 512, 0, stream>>>(W+OF_MU, W+OF_HF, W+OF_HB, W+OF_HP);
  k_head<<<32, 512, 0, stream>>>(W+OF_HP, Wv, Wout, Wh, bh, out);
  k_z<<<64, 256, 0, stream>>>(W+OF_MU, lengths, out);
}

// Round 3
// 966.143 us; speedup vs baseline: 22.0521x; 22.0521x over previous
//
#include <hip/hip_runtime.h>
#include <hip/hip_bf16.h>
#include <math.h>

// Problem constants
#define B_   32
#define S_   512
#define V_   30000
#define E_   300
#define H_   200
#define NH_  4
#define ENC_ 400
#define G4_  800     // 4*H
#define NEGV  (-1e9f)
#define SCALE_ 1000.0f

typedef _Float16 half2v __attribute__((ext_vector_type(2)));

#if defined(__has_builtin)
#if __has_builtin(__builtin_amdgcn_fdot2)
#define FDOT2(a,b,c) __builtin_amdgcn_fdot2((a),(b),(c),false)
#endif
#endif
#ifndef FDOT2
#define FDOT2(a,b,c) fmaf((float)(a)[1],(float)(b)[1], fmaf((float)(a)[0],(float)(b)[0],(c)))
#endif

// ---- workspace layout (float offsets) ----
#define OF_QVEC  320000ull     // q_state @ W_q  [400]
#define OF_WKQ   320448ull     // wkq [400][4]
#define OF_THETA 322048ull     // scores [B][4][512]
#define OF_MU    387584ull     // mu     [B][4][512]
#define OF_HP    453120ull     // hp [B][4][400]
#define OF_LEN   504320ull     // lengths (int) [32]
#define OF_XWF   504384ull     // xW forward  [B*S][800]
#define OF_XWB   13611584ull   // xW backward (natural s order) [B*S][800]
#define OF_HF    26718784ull   // h_f [B*S][200]
#define OF_HB    29995584ull   // h_b [B*S][200]

// -------- lengths from mask (dtype auto-detect: u8 / i32 / i64) --------
__global__ void k_lengths(const void* __restrict__ mask, int* __restrict__ lengths) {
  int b = blockIdx.x, lane = threadIdx.x;
  const unsigned char* mb = (const unsigned char*)mask;
  int mode;
  if (mb[1] != 0) mode = 0;
  else if (((const int*)mask)[1] != 0) mode = 1;
  else mode = 2;
  int cnt = 0;
  for (int s = lane; s < S_; s += 64) {
    int v;
    if (mode == 0)      v = mb[b*S_ + s] ? 1 : 0;
    else if (mode == 1) v = ((const int*)mask)[b*S_ + s] ? 1 : 0;
    else                v = ((const long long*)mask)[b*S_ + s] ? 1 : 0;
    cnt += v;
  }
  for (int off = 32; off; off >>= 1) cnt += __shfl_xor(cnt, off);
  if (lane == 0) lengths[b] = cnt;
}

// -------- qvec = q_state @ W_q --------
__global__ void k_qvec(const float* __restrict__ qs, const float* __restrict__ Wq,
                       float* __restrict__ qvec) {
  __shared__ float qsl[ENC_];
  int t = threadIdx.x;
  if (t < ENC_) qsl[t] = qs[t];
  __syncthreads();
  if (t < ENC_) {
    float acc = 0.f;
    for (int i = 0; i < ENC_; ++i) acc += qsl[i] * Wq[(size_t)i*ENC_ + t];
    qvec[t] = acc;
  }
}

// -------- wkq[e][head] --------
__global__ void k_wkq(const float* __restrict__ Wk, const float* __restrict__ qvec,
                      float* __restrict__ wkq) {
  int t = threadIdx.x;
  int e = blockIdx.x*64 + (t >> 2);
  int head = t & 3;
  if (e < ENC_) {
    float acc = 0.f;
    const float* row = Wk + (size_t)e*ENC_ + head*100;
    const float* qv  = qvec + head*100;
    for (int d = 0; d < 100; ++d) acc += row[d]*qv[d];
    wkq[e*4 + head] = acc;
  }
}

// -------- input projections GEMM (unchanged) --------
__global__ __launch_bounds__(256) void k_gemm_in(
    const int* __restrict__ x, const float* __restrict__ emb,
    const float* __restrict__ wf, const float* __restrict__ wb,
    const float* __restrict__ bf, const float* __restrict__ bb,
    float* __restrict__ xWf, float* __restrict__ xWb)
{
  __shared__ int xid[128];
  __shared__ __align__(16) float sA[16][128];
  __shared__ __align__(16) float sB[16][64];
  const int t = threadIdx.x;
  const int row0 = blockIdx.x * 128;
  const int col0 = blockIdx.y * 64;
  if (t < 128) xid[t] = x[row0 + t];
  __syncthreads();
  float acc[8][4];
  #pragma unroll
  for (int i = 0; i < 8; ++i)
    #pragma unroll
    for (int j = 0; j < 4; ++j) acc[i][j] = 0.f;
  const int y = t >> 4, xq = t & 15;
  const int rl = t >> 1, half = t & 1;
  const int cb = t & 63, kq = t >> 6;
  const int colg_b = col0 + cb;
  const float* wsrc = (colg_b < 800) ? (wf + (size_t)colg_b*300)
                                     : (wb + (size_t)(colg_b-800)*300);
  const float* asrc = emb + (size_t)xid[rl]*300;
  for (int kc = 0; kc < 19; ++kc) {
    const int k0 = kc*16;
    {
      const int kb = k0 + half*8;
      const float* src = asrc + kb;
      if (kb + 7 < 300) {
        float4 a  = *(const float4*)(src);
        float4 b4 = *(const float4*)(src+4);
        sA[half*8+0][rl]=a.x;  sA[half*8+1][rl]=a.y;  sA[half*8+2][rl]=a.z;  sA[half*8+3][rl]=a.w;
        sA[half*8+4][rl]=b4.x; sA[half*8+5][rl]=b4.y; sA[half*8+6][rl]=b4.z; sA[half*8+7][rl]=b4.w;
      } else {
        #pragma unroll
        for (int i = 0; i < 8; ++i) sA[half*8+i][rl] = (kb+i < 300) ? src[i] : 0.f;
      }
    }
    {
      const int kb = k0 + kq*4;
      if (kb + 3 < 300) {
        float4 w4 = *(const float4*)(wsrc + kb);
        sB[kq*4+0][cb]=w4.x; sB[kq*4+1][cb]=w4.y; sB[kq*4+2][cb]=w4.z; sB[kq*4+3][cb]=w4.w;
      } else {
        #pragma unroll
        for (int i = 0; i < 4; ++i) sB[kq*4+i][cb] = (kb+i < 300) ? wsrc[kb+i] : 0.f;
      }
    }
    __syncthreads();
    #pragma unroll
    for (int k = 0; k < 16; ++k) {
      float4 a0 = *(const float4*)&sA[k][y*8];
      float4 a1 = *(const float4*)&sA[k][y*8+4];
      float4 b4 = *(const float4*)&sB[k][xq*4];
      float av[8] = {a0.x,a0.y,a0.z,a0.w,a1.x,a1.y,a1.z,a1.w};
      float bv[4] = {b4.x,b4.y,b4.z,b4.w};
      #pragma unroll
      for (int i = 0; i < 8; ++i)
        #pragma unroll
        for (int j = 0; j < 4; ++j) acc[i][j] += av[i]*bv[j];
    }
    __syncthreads();
  }
  const int colg = col0 + xq*4;
  const bool isF = (colg < 800);
  const int colo = isF ? colg : (colg - 800);
  float4 bias = isF ? *(const float4*)(bf + colo) : *(const float4*)(bb + colo);
  float* dst = isF ? xWf : xWb;
  #pragma unroll
  for (int i = 0; i < 8; ++i) {
    int row = row0 + y*8 + i;
    float4 o = {acc[i][0]+bias.x, acc[i][1]+bias.y, acc[i][2]+bias.z, acc[i][3]+bias.w};
    *(float4*)(dst + (size_t)row*800 + colo) = o;
  }
}

// -------- fp16 weight-stationary single-WG LSTM --------
// One WG (512 thr) per (dir,b) chain; 64 WGs total. Thread t holds rows
// {t, t+512} of W_hh (1024-row padded) as 2x100 packed half2 in VGPRs —
// full k per row, so NO cross-thread reduction. Recurrent h is fp16 in LDS
// (wave-uniform b128 broadcast reads); gates/c/h and xW stay fp32.
// Per step: prefetch xW row -> 200 v_dot2_f32_f16 -> sums[1024] LDS ->
// barrier -> threads<200 elementwise (c in reg), write h fp32 global +
// fp16 LDS -> barrier. No atomics, no inter-WG sync.
__global__ __launch_bounds__(512, 2) void k_lstm_ws(
    const float* __restrict__ xWf, const float* __restrict__ xWb,
    const float* __restrict__ whhf, const float* __restrict__ whhb,
    const int* __restrict__ lengths,
    float* __restrict__ h_f, float* __restrict__ h_b)
{
  const int bid = blockIdx.x;
  const int dir = bid >> 5, b = bid & 31;
  const float* __restrict__ xW  = dir ? xWb : xWf;
  const float* __restrict__ whh = dir ? whhb : whhf;
  float* __restrict__ hout      = dir ? h_b : h_f;
  const int len = lengths[b];
  const int t = threadIdx.x;

  __shared__ __align__(16) _Float16 hb[256];
  __shared__ float sums[1024];

  // ---- one-time weight preload: rows t and t+512 (pad rows -> 0) ----
  half2v w0[100], w1[100];
  {
    const float* r0p = whh + (size_t)t*H_;
    #pragma unroll
    for (int j = 0; j < 50; ++j) {
      float4 a = *(const float4*)(r0p + 4*j);
      w0[2*j]   = half2v{(_Float16)a.x, (_Float16)a.y};
      w0[2*j+1] = half2v{(_Float16)a.z, (_Float16)a.w};
    }
    if (t < 288) {
      const float* r1p = whh + (size_t)(512+t)*H_;
      #pragma unroll
      for (int j = 0; j < 50; ++j) {
        float4 a = *(const float4*)(r1p + 4*j);
        w1[2*j]   = half2v{(_Float16)a.x, (_Float16)a.y};
        w1[2*j+1] = half2v{(_Float16)a.z, (_Float16)a.w};
      }
    } else {
      #pragma unroll
      for (int j = 0; j < 100; ++j) w1[j] = half2v{(_Float16)0.f, (_Float16)0.f};
    }
  }

  if (t < 256) hb[t] = (_Float16)0.f;
  float cst = 0.f;
  __syncthreads();

  for (int step = 0; step < len; ++step) {
    const int pos = dir ? (len-1-step) : step;
    // prefetch xW gate inputs (consumed after barrier; hides L2 latency)
    float xi=0.f, xf=0.f, xg=0.f, xo=0.f;
    if (t < H_) {
      const float* xr = xW + ((size_t)b*S_ + pos)*G4_ + t;
      xi = xr[0]; xf = xr[H_]; xg = xr[2*H_]; xo = xr[3*H_];
    }
    float a0 = 0.f, a1 = 0.f;
    #pragma unroll
    for (int j = 0; j < 25; ++j) {
      float4 h4 = *(const float4*)&hb[8*j];   // wave-uniform broadcast
      half2v p0 = __builtin_bit_cast(half2v, h4.x);
      half2v p1 = __builtin_bit_cast(half2v, h4.y);
      half2v p2 = __builtin_bit_cast(half2v, h4.z);
      half2v p3 = __builtin_bit_cast(half2v, h4.w);
      a0 = FDOT2(w0[4*j],   p0, a0);
      a0 = FDOT2(w0[4*j+1], p1, a0);
      a0 = FDOT2(w0[4*j+2], p2, a0);
      a0 = FDOT2(w0[4*j+3], p3, a0);
      a1 = FDOT2(w1[4*j],   p0, a1);
      a1 = FDOT2(w1[4*j+1], p1, a1);
      a1 = FDOT2(w1[4*j+2], p2, a1);
      a1 = FDOT2(w1[4*j+3], p3, a1);
    }
    sums[t] = a0;
    sums[512+t] = a1;
    __syncthreads();
    if (t < H_) {
      float gi = sums[t]        + xi;
      float gf = sums[H_ + t]   + xf;
      float gg = sums[2*H_ + t] + xg;
      float go = sums[3*H_ + t] + xo;
      float ig = 1.f/(1.f+__expf(-gi));
      float fg = 1.f/(1.f+__expf(-gf));
      float og = 1.f/(1.f+__expf(-go));
      float ggc = fminf(fmaxf(gg, -10.f), 10.f);
      float eg = __expf(2.f*ggc);
      cst = fg*cst + ig*((eg-1.f)/(eg+1.f));
      float cc = fminf(fmaxf(cst, -10.f), 10.f);
      float ec = __expf(2.f*cc);
      float hn = og*((ec-1.f)/(ec+1.f));
      hout[((size_t)b*S_ + pos)*H_ + t] = hn;
      hb[t] = (_Float16)hn;
    }
    __syncthreads();
  }
}

// -------- scores --------
__global__ __launch_bounds__(256) void k_scores(
    const float* __restrict__ hf, const float* __restrict__ hb,
    const float* __restrict__ wkq, const int* __restrict__ lengths,
    float* __restrict__ theta)
{
  int wid = blockIdx.x*4 + (threadIdx.x >> 6);
  int lane = threadIdx.x & 63;
  int b = wid >> 9, s = wid & 511;
  const float* hfr = hf + ((size_t)b*S_ + s)*H_;
  const float* hbr = hb + ((size_t)b*S_ + s)*H_;
  float a0=0.f, a1=0.f, a2=0.f, a3=0.f;
  for (int e = lane; e < ENC_; e += 64) {
    float hv = (e < H_) ? hfr[e] : hbr[e-H_];
    float4 w = *(const float4*)(wkq + e*4);
    a0 += hv*w.x; a1 += hv*w.y; a2 += hv*w.z; a3 += hv*w.w;
  }
  for (int off = 32; off; off >>= 1) {
    a0 += __shfl_xor(a0, off); a1 += __shfl_xor(a1, off);
    a2 += __shfl_xor(a2, off); a3 += __shfl_xor(a3, off);
  }
  if (lane == 0) {
    bool valid = s < lengths[b];
    size_t base = (size_t)b*2048 + s;
    theta[base       ] = valid ? SCALE_*a0 : NEGV;
    theta[base +  512] = valid ? SCALE_*a1 : NEGV;
    theta[base + 1024] = valid ? SCALE_*a2 : NEGV;
    theta[base + 1536] = valid ? SCALE_*a3 : NEGV;
  }
}

// -------- sparseMAP budget projection --------
__global__ void k_sparsemap(const float* __restrict__ theta, const int* __restrict__ lengths,
                            float* __restrict__ mu) {
  int pid = blockIdx.x;
  int lane = threadIdx.x;
  const float* th = theta + (size_t)pid*512;
  float v[8];
  #pragma unroll
  for (int i = 0; i < 8; ++i) v[i] = th[i*64 + lane];
  float kf = rintf(0.2f * (float)lengths[pid >> 2]);
  float mn = v[0], mx = v[0];
  #pragma unroll
  for (int i = 1; i < 8; ++i) { mn = fminf(mn, v[i]); mx = fmaxf(mx, v[i]); }
  for (int off = 32; off; off >>= 1) {
    mn = fminf(mn, __shfl_xor(mn, off)); mx = fmaxf(mx, __shfl_xor(mx, off));
  }
  float lo = mn - 1.f, hi = mx;
  for (int it = 0; it < 60; ++it) {
    float mid = 0.5f*(lo + hi);
    float s = 0.f;
    #pragma unroll
    for (int i = 0; i < 8; ++i) s += fminf(fmaxf(v[i]-mid, 0.f), 1.f);
    for (int off = 32; off; off >>= 1) s += __shfl_xor(s, off);
    bool big = s > kf;
    lo = big ? mid : lo;
    hi = big ? hi : mid;
  }
  float tau0 = 0.5f*(lo + hi);
  float fs = 0.f, nU = 0.f, nS = 0.f;
  #pragma unroll
  for (int i = 0; i < 8; ++i) {
    float m0 = v[i] - tau0;
    if (m0 >= 1.f) nU += 1.f;
    else if (m0 > 0.f) { fs += v[i]; nS += 1.f; }
  }
  for (int off = 32; off; off >>= 1) {
    fs += __shfl_xor(fs, off); nU += __shfl_xor(nU, off); nS += __shfl_xor(nS, off);
  }
  float tau = (fs + nU - kf) / fmaxf(nS, 1.f);
  tau = (nS > 0.f) ? tau : tau0;
  float* mo = mu + (size_t)pid*512;
  #pragma unroll
  for (int i = 0; i < 8; ++i) mo[i*64 + lane] = fminf(fmaxf(v[i]-tau, 0.f), 1.f);
}

// -------- hp[b,head,e] = sum_s mu * h --------
__global__ __launch_bounds__(512) void k_hp(
    const float* __restrict__ mu, const float* __restrict__ hf,
    const float* __restrict__ hb, float* __restrict__ hp)
{
  __shared__ float mul[512];
  int pid = blockIdx.x, b = pid >> 2;
  int t = threadIdx.x;
  mul[t] = mu[(size_t)pid*512 + t];
  __syncthreads();
  if (t < ENC_) {
    const float* hsrc = (t < H_) ? (hf + t) : (hb + (t - H_));
    float acc = 0.f;
    for (int s = 0; s < 512; ++s) {
      float m = mul[s];
      if (m != 0.f) acc += m * hsrc[((size_t)b*S_ + s)*H_];
    }
    hp[(size_t)pid*ENC_ + t] = acc;
  }
}

// -------- head --------
__global__ __launch_bounds__(512) void k_head(
    const float* __restrict__ hp, const float* __restrict__ Wv,
    const float* __restrict__ Wout, const float* __restrict__ Wh,
    const float* __restrict__ bh, float* __restrict__ out)
{
  __shared__ float hpl[1600];
  __shared__ float ppl[ENC_];
  __shared__ float ojl[ENC_];
  __shared__ float red[512];
  int b = blockIdx.x, t = threadIdx.x;
  for (int i = t; i < 1600; i += 512) hpl[i] = hp[(size_t)b*1600 + i];
  __syncthreads();
  if (t < ENC_) {
    int head = t / 100;
    float acc = 0.f;
    for (int e = 0; e < ENC_; ++e) acc += hpl[head*ENC_ + e] * Wv[(size_t)e*ENC_ + t];
    ppl[t] = acc;
  }
  __syncthreads();
  if (t < ENC_) {
    float acc = 0.f;
    for (int c = 0; c < ENC_; ++c) acc += ppl[c] * Wout[(size_t)c*ENC_ + t];
    ojl[t] = acc;
  }
  __syncthreads();
  red[t] = (t < ENC_) ? ojl[t]*Wh[t] : 0.f;
  __syncthreads();
  for (int sft = 256; sft; sft >>= 1) {
    if (t < sft) red[t] += red[t+sft];
    __syncthreads();
  }
  if (t == 0) out[b] = 1.f/(1.f + expf(-(red[0] + bh[0])));
}

// -------- z --------
__global__ void k_z(const float* __restrict__ mu, const int* __restrict__ lengths,
                    float* __restrict__ out) {
  int idx = blockIdx.x*256 + threadIdx.x;
  int b = idx >> 9, s = idx & 511;
  float zz = 0.f;
  if (s < lengths[b]) {
    size_t base = (size_t)b*2048 + s;
    zz = 0.25f*(mu[base] + mu[base+512] + mu[base+1024] + mu[base+1536]);
  }
  out[32 + idx] = zz;
}

extern "C" void kernel_launch(void* const* d_in, const int* in_sizes, int n_in,
                              void* d_out, int out_size, void* d_ws, size_t ws_size,
                              hipStream_t stream) {
  const int*   x    = (const int*)d_in[0];
  const void*  mask = d_in[1];
  const float* emb  = (const float*)d_in[2];
  const float* wihf = (const float*)d_in[3];
  const float* whhf = (const float*)d_in[4];
  const float* bf   = (const float*)d_in[5];
  const float* wihb = (const float*)d_in[6];
  const float* whhb = (const float*)d_in[7];
  const float* bb   = (const float*)d_in[8];
  const float* qs   = (const float*)d_in[9];
  const float* Wq   = (const float*)d_in[10];
  const float* Wk   = (const float*)d_in[11];
  const float* Wv   = (const float*)d_in[12];
  const float* Wout = (const float*)d_in[13];
  const float* Wh   = (const float*)d_in[14];
  const float* bh   = (const float*)d_in[15];
  float* out = (float*)d_out;
  float* W = (float*)d_ws;
  int* lengths = (int*)(W + OF_LEN);

  k_lengths<<<32, 64, 0, stream>>>(mask, lengths);
  k_qvec<<<1, 512, 0, stream>>>(qs, Wq, W+OF_QVEC);
  k_wkq<<<7, 256, 0, stream>>>(Wk, W+OF_QVEC, W+OF_WKQ);
  hipMemsetAsync(W+OF_HF, 0, (size_t)B_*S_*H_*sizeof(float), stream);
  hipMemsetAsync(W+OF_HB, 0, (size_t)B_*S_*H_*sizeof(float), stream);
  k_gemm_in<<<dim3(128, 25), 256, 0, stream>>>(x, emb, wihf, wihb, bf, bb,
                                               W+OF_XWF, W+OF_XWB);
  k_lstm_ws<<<64, 512, 0, stream>>>(W+OF_XWF, W+OF_XWB, whhf, whhb,
                                    lengths, W+OF_HF, W+OF_HB);
  k_scores<<<4096, 256, 0, stream>>>(W+OF_HF, W+OF_HB, W+OF_WKQ, lengths, W+OF_THETA);
  k_sparsemap<<<128, 64, 0, stream>>>(W+OF_THETA, lengths, W+OF_MU);
  k_hp<<<128, 512, 0, stream>>>(W+OF_MU, W+OF_HF, W+OF_HB, W+OF_HP);
  k_head<<<32, 512, 0, stream>>>(W+OF_HP, Wv, Wout, Wh, bh, out);
  k_z<<<64, 256, 0, stream>>>(W+OF_MU, lengths, out);
}

// Round 4
// 877.568 us; speedup vs baseline: 24.2779x; 1.1009x over previous
//
#include <hip/hip_runtime.h>
#include <hip/hip_bf16.h>
#include <math.h>

// Problem constants
#define B_   32
#define S_   512
#define V_   30000
#define E_   300
#define H_   200
#define NH_  4
#define ENC_ 400
#define G4_  800     // 4*H
#define NEGV  (-1e9f)
#define SCALE_ 1000.0f

typedef _Float16 half2v __attribute__((ext_vector_type(2)));
typedef _Float16 f16x8  __attribute__((ext_vector_type(8)));
typedef float    f32x4  __attribute__((ext_vector_type(4)));

#if defined(__has_builtin)
#if __has_builtin(__builtin_amdgcn_fdot2)
#define FDOT2(a,b,c) __builtin_amdgcn_fdot2((a),(b),(c),false)
#endif
#endif
#ifndef FDOT2
#define FDOT2(a,b,c) fmaf((float)(a)[1],(float)(b)[1], fmaf((float)(a)[0],(float)(b)[0],(c)))
#endif

// ---- workspace layout (float offsets) ----
#define OF_QVEC  320000ull     // q_state @ W_q  [400]
#define OF_WKQ   320448ull     // wkq [400][4]
#define OF_THETA 322048ull     // scores [B][4][512]
#define OF_MU    387584ull     // mu     [B][4][512]
#define OF_HP    453120ull     // hp [B][4][400]
#define OF_LEN   504320ull     // lengths (int) [32]
#define OF_XWF   504384ull     // xW forward  [B*S][800]
#define OF_XWB   13611584ull   // xW backward (natural s order) [B*S][800]
#define OF_HF    26718784ull   // h_f [B*S][200]
#define OF_HB    29995584ull   // h_b [B*S][200]

// -------- lengths from mask (dtype auto-detect: u8 / i32 / i64) --------
__global__ void k_lengths(const void* __restrict__ mask, int* __restrict__ lengths) {
  int b = blockIdx.x, lane = threadIdx.x;
  const unsigned char* mb = (const unsigned char*)mask;
  int mode;
  if (mb[1] != 0) mode = 0;
  else if (((const int*)mask)[1] != 0) mode = 1;
  else mode = 2;
  int cnt = 0;
  for (int s = lane; s < S_; s += 64) {
    int v;
    if (mode == 0)      v = mb[b*S_ + s] ? 1 : 0;
    else if (mode == 1) v = ((const int*)mask)[b*S_ + s] ? 1 : 0;
    else                v = ((const long long*)mask)[b*S_ + s] ? 1 : 0;
    cnt += v;
  }
  for (int off = 32; off; off >>= 1) cnt += __shfl_xor(cnt, off);
  if (lane == 0) lengths[b] = cnt;
}

// -------- qvec = q_state @ W_q --------
__global__ void k_qvec(const float* __restrict__ qs, const float* __restrict__ Wq,
                       float* __restrict__ qvec) {
  __shared__ float qsl[ENC_];
  int t = threadIdx.x;
  if (t < ENC_) qsl[t] = qs[t];
  __syncthreads();
  if (t < ENC_) {
    float acc = 0.f;
    for (int i = 0; i < ENC_; ++i) acc += qsl[i] * Wq[(size_t)i*ENC_ + t];
    qvec[t] = acc;
  }
}

// -------- wkq[e][head] --------
__global__ void k_wkq(const float* __restrict__ Wk, const float* __restrict__ qvec,
                      float* __restrict__ wkq) {
  int t = threadIdx.x;
  int e = blockIdx.x*64 + (t >> 2);
  int head = t & 3;
  if (e < ENC_) {
    float acc = 0.f;
    const float* row = Wk + (size_t)e*ENC_ + head*100;
    const float* qv  = qvec + head*100;
    for (int d = 0; d < 100; ++d) acc += row[d]*qv[d];
    wkq[e*4 + head] = acc;
  }
}

// -------- input projections via fp16 MFMA --------
// C [16384 x 1600] = gather(emb)[16384 x 300] @ [wf|wb]^T, K padded to 320.
// Tile 128x64, 256 thr = 4 waves (2x2), each wave 64x32 out = 4x2 mfma frags.
// Frag layout: A row = l&15, k = 8*(l>>4)+j ; B col = l&15, same k.
// C layout (m89-verified): col = l&15, row = 4*(l>>4)+reg.
__global__ __launch_bounds__(256) void k_gemm_mfma(
    const int* __restrict__ x, const float* __restrict__ emb,
    const float* __restrict__ wf, const float* __restrict__ wb,
    const float* __restrict__ bf, const float* __restrict__ bb,
    float* __restrict__ xWf, float* __restrict__ xWb)
{
  __shared__ int xid[128];
  __shared__ __align__(16) _Float16 sA[128][40];  // pad 8: 16B-aligned rows, 2-way banks
  __shared__ __align__(16) _Float16 sB[64][40];
  const int t = threadIdx.x;
  const int row0 = blockIdx.x * 128;
  const int col0 = blockIdx.y * 64;
  if (t < 128) xid[t] = x[row0 + t];
  const int w = t >> 6, lane = t & 63;
  const int wr = w >> 1, wc = w & 1;
  f32x4 acc[4][2] = {};
  const int ar = t >> 1, ah = t & 1;         // A staging: row ar, k-half ah*16
  const int bc = t >> 2, bq = t & 3;         // B staging: col bc, k-q bq*8
  const int colg = col0 + bc;
  const float* wsrc = (colg < 800) ? (wf + (size_t)colg*300)
                                   : (wb + (size_t)(colg-800)*300);
  __syncthreads();
  const float* asrc = emb + (size_t)xid[ar]*300;
  for (int kc = 0; kc < 10; ++kc) {
    const int k0 = kc*32;
    { // stage A: 16 fp16 per thread
      const int kb = k0 + ah*16;
      _Float16 tmp[16];
      if (kb + 15 < 300) {
        #pragma unroll
        for (int q = 0; q < 4; ++q) {
          float4 a = *(const float4*)(asrc + kb + 4*q);
          tmp[4*q]  =(_Float16)a.x; tmp[4*q+1]=(_Float16)a.y;
          tmp[4*q+2]=(_Float16)a.z; tmp[4*q+3]=(_Float16)a.w;
        }
      } else {
        #pragma unroll
        for (int i = 0; i < 16; ++i)
          tmp[i] = (_Float16)((kb+i < 300) ? asrc[kb+i] : 0.f);
      }
      *(f16x8*)&sA[ar][ah*16]   = *(f16x8*)&tmp[0];
      *(f16x8*)&sA[ar][ah*16+8] = *(f16x8*)&tmp[8];
    }
    { // stage B: 8 fp16 per thread
      const int kb = k0 + bq*8;
      _Float16 tmp[8];
      if (kb + 7 < 300) {
        #pragma unroll
        for (int q = 0; q < 2; ++q) {
          float4 a = *(const float4*)(wsrc + kb + 4*q);
          tmp[4*q]  =(_Float16)a.x; tmp[4*q+1]=(_Float16)a.y;
          tmp[4*q+2]=(_Float16)a.z; tmp[4*q+3]=(_Float16)a.w;
        }
      } else {
        #pragma unroll
        for (int i = 0; i < 8; ++i)
          tmp[i] = (_Float16)((kb+i < 300) ? wsrc[kb+i] : 0.f);
      }
      *(f16x8*)&sB[bc][bq*8] = *(f16x8*)&tmp[0];
    }
    __syncthreads();
    const int fr = lane & 15, kg = lane >> 4;
    f16x8 b0 = *(const f16x8*)&sB[wc*32 + fr][kg*8];
    f16x8 b1 = *(const f16x8*)&sB[wc*32 + 16 + fr][kg*8];
    #pragma unroll
    for (int m = 0; m < 4; ++m) {
      f16x8 afrag = *(const f16x8*)&sA[wr*64 + m*16 + fr][kg*8];
      acc[m][0] = __builtin_amdgcn_mfma_f32_16x16x32_f16(afrag, b0, acc[m][0], 0,0,0);
      acc[m][1] = __builtin_amdgcn_mfma_f32_16x16x32_f16(afrag, b1, acc[m][1], 0,0,0);
    }
    __syncthreads();
  }
  const int crb = (lane >> 4) * 4, ccol = lane & 15;
  #pragma unroll
  for (int n = 0; n < 2; ++n) {
    int colg2 = col0 + wc*32 + n*16 + ccol;
    bool isF = colg2 < 800;
    int colo = isF ? colg2 : colg2 - 800;
    float bias = isF ? bf[colo] : bb[colo];
    float* dst = isF ? xWf : xWb;
    #pragma unroll
    for (int m = 0; m < 4; ++m) {
      int row = row0 + wr*64 + m*16 + crb;
      #pragma unroll
      for (int r = 0; r < 4; ++r)
        dst[(size_t)(row+r)*800 + colo] = acc[m][n][r] + bias;
    }
  }
}

// -------- fp16 weight-stationary LSTM v2: 1 gate-row/thread, no spill --------
// 64 WGs (one per dir,b chain) x 1024 thr (16 waves; launch_bounds caps VGPR
// at 128 -> 4 waves/SIMD, full residency). Thread t<800 holds W_hh row t as
// 100 packed half2 VGPRs: w[m] = W[t][2m..2m+1]. Per step:
//   coalesced xv load -> 100 fdot2 vs fp16 h broadcast from LDS ->
//   own-gate nonlinearity (tanh for rows 400..599, sigmoid otherwise) ->
//   gact[t] -> barrier -> t<200: c = fg*c + ig*gg; h = og*tanh(c);
//   publish h (global fp32 + LDS fp16) -> barrier.
__global__ __launch_bounds__(1024) void k_lstm_v2(
    const float* __restrict__ xWf, const float* __restrict__ xWb,
    const float* __restrict__ whhf, const float* __restrict__ whhb,
    const int* __restrict__ lengths,
    float* __restrict__ h_f, float* __restrict__ h_b)
{
  const int bid = blockIdx.x;
  const int dir = bid >> 5, b = bid & 31;
  const float* __restrict__ xW  = dir ? xWb : xWf;
  const float* __restrict__ whh = dir ? whhb : whhf;
  float* __restrict__ hout      = dir ? h_b : h_f;
  const int len = lengths[b];
  const int t = threadIdx.x;
  const int active = (t < G4_);

  __shared__ __align__(16) _Float16 hbh[200];
  __shared__ float gact[G4_];

  // one-time weight preload: w[m] = row t, k = 2m..2m+1 (m = 0..99)
  half2v w[100];
  if (active) {
    const float* rp = whh + (size_t)t*H_;
    #pragma unroll
    for (int j = 0; j < 50; ++j) {
      float2 a = *(const float2*)(rp + 2*j);
      w[j] = half2v{(_Float16)a.x, (_Float16)a.y};
    }
    #pragma unroll
    for (int j = 0; j < 50; ++j) {
      float2 a = *(const float2*)(rp + 100 + 2*j);
      w[50+j] = half2v{(_Float16)a.x, (_Float16)a.y};
    }
  }
  if (t < 200) hbh[t] = (_Float16)0.f;
  float cst = 0.f;
  const float* xbase = xW + (size_t)b*S_*G4_;
  const int isTanh = (t >= 400) && (t < 600);
  __syncthreads();

  for (int step = 0; step < len; ++step) {
    const int pos = dir ? (len-1-step) : step;
    if (active) {
      float xv = xbase[(size_t)pos*G4_ + t];     // coalesced; hides under dot
      float a0 = 0.f, a1 = 0.f;
      // first 100 h-elements (k=0..99) pair with w[0..49]
      #pragma unroll
      for (int j = 0; j < 12; ++j) {             // k = 0..95
        float4 h4 = *(const float4*)&hbh[8*j];
        a0 = FDOT2(w[4*j],   __builtin_bit_cast(half2v, h4.x), a0);
        a1 = FDOT2(w[4*j+1], __builtin_bit_cast(half2v, h4.y), a1);
        a0 = FDOT2(w[4*j+2], __builtin_bit_cast(half2v, h4.z), a0);
        a1 = FDOT2(w[4*j+3], __builtin_bit_cast(half2v, h4.w), a1);
      }
      { // k = 96..99
        float2 h2 = *(const float2*)&hbh[96];
        a0 = FDOT2(w[48], __builtin_bit_cast(half2v, h2.x), a0);
        a1 = FDOT2(w[49], __builtin_bit_cast(half2v, h2.y), a1);
      }
      // k = 100..199 pair with w[50..99]
      #pragma unroll
      for (int j = 0; j < 12; ++j) {             // k = 100..195
        float4 h4 = *(const float4*)&hbh[100 + 8*j];
        a0 = FDOT2(w[50+4*j],   __builtin_bit_cast(half2v, h4.x), a0);
        a1 = FDOT2(w[50+4*j+1], __builtin_bit_cast(half2v, h4.y), a1);
        a0 = FDOT2(w[50+4*j+2], __builtin_bit_cast(half2v, h4.z), a0);
        a1 = FDOT2(w[50+4*j+3], __builtin_bit_cast(half2v, h4.w), a1);
      }
      { // k = 196..199
        float2 h2 = *(const float2*)&hbh[196];
        a0 = FDOT2(w[98], __builtin_bit_cast(half2v, h2.x), a0);
        a1 = FDOT2(w[99], __builtin_bit_cast(half2v, h2.y), a1);
      }
      float pre = a0 + a1 + xv;
      float act;
      if (isTanh) {
        float gc = fminf(fmaxf(pre, -10.f), 10.f);
        float e2 = __expf(2.f*gc);
        act = (e2-1.f)/(e2+1.f);
      } else {
        act = 1.f/(1.f+__expf(-pre));
      }
      gact[t] = act;
    }
    __syncthreads();
    if (t < 200) {
      float ig = gact[t], fg = gact[200+t], gg = gact[400+t], og = gact[600+t];
      cst = fg*cst + ig*gg;
      float cc = fminf(fmaxf(cst, -10.f), 10.f);
      float ec = __expf(2.f*cc);
      float hn = og*((ec-1.f)/(ec+1.f));
      hout[((size_t)b*S_ + pos)*H_ + t] = hn;
      hbh[t] = (_Float16)hn;
    }
    __syncthreads();
  }
}

// -------- scores --------
__global__ __launch_bounds__(256) void k_scores(
    const float* __restrict__ hf, const float* __restrict__ hb,
    const float* __restrict__ wkq, const int* __restrict__ lengths,
    float* __restrict__ theta)
{
  int wid = blockIdx.x*4 + (threadIdx.x >> 6);
  int lane = threadIdx.x & 63;
  int b = wid >> 9, s = wid & 511;
  const float* hfr = hf + ((size_t)b*S_ + s)*H_;
  const float* hbr = hb + ((size_t)b*S_ + s)*H_;
  bool valid = s < lengths[b];
  float a0=0.f, a1=0.f, a2=0.f, a3=0.f;
  if (valid) {
    for (int e = lane; e < ENC_; e += 64) {
      float hv = (e < H_) ? hfr[e] : hbr[e-H_];
      float4 w = *(const float4*)(wkq + e*4);
      a0 += hv*w.x; a1 += hv*w.y; a2 += hv*w.z; a3 += hv*w.w;
    }
    for (int off = 32; off; off >>= 1) {
      a0 += __shfl_xor(a0, off); a1 += __shfl_xor(a1, off);
      a2 += __shfl_xor(a2, off); a3 += __shfl_xor(a3, off);
    }
  }
  if (lane == 0) {
    size_t base = (size_t)b*2048 + s;
    theta[base       ] = valid ? SCALE_*a0 : NEGV;
    theta[base +  512] = valid ? SCALE_*a1 : NEGV;
    theta[base + 1024] = valid ? SCALE_*a2 : NEGV;
    theta[base + 1536] = valid ? SCALE_*a3 : NEGV;
  }
}

// -------- sparseMAP budget projection --------
__global__ void k_sparsemap(const float* __restrict__ theta, const int* __restrict__ lengths,
                            float* __restrict__ mu) {
  int pid = blockIdx.x;
  int lane = threadIdx.x;
  const float* th = theta + (size_t)pid*512;
  float v[8];
  #pragma unroll
  for (int i = 0; i < 8; ++i) v[i] = th[i*64 + lane];
  float kf = rintf(0.2f * (float)lengths[pid >> 2]);
  float mn = v[0], mx = v[0];
  #pragma unroll
  for (int i = 1; i < 8; ++i) { mn = fminf(mn, v[i]); mx = fmaxf(mx, v[i]); }
  for (int off = 32; off; off >>= 1) {
    mn = fminf(mn, __shfl_xor(mn, off)); mx = fmaxf(mx, __shfl_xor(mx, off));
  }
  float lo = mn - 1.f, hi = mx;
  for (int it = 0; it < 60; ++it) {
    float mid = 0.5f*(lo + hi);
    float s = 0.f;
    #pragma unroll
    for (int i = 0; i < 8; ++i) s += fminf(fmaxf(v[i]-mid, 0.f), 1.f);
    for (int off = 32; off; off >>= 1) s += __shfl_xor(s, off);
    bool big = s > kf;
    lo = big ? mid : lo;
    hi = big ? hi : mid;
  }
  float tau0 = 0.5f*(lo + hi);
  float fs = 0.f, nU = 0.f, nS = 0.f;
  #pragma unroll
  for (int i = 0; i < 8; ++i) {
    float m0 = v[i] - tau0;
    if (m0 >= 1.f) nU += 1.f;
    else if (m0 > 0.f) { fs += v[i]; nS += 1.f; }
  }
  for (int off = 32; off; off >>= 1) {
    fs += __shfl_xor(fs, off); nU += __shfl_xor(nU, off); nS += __shfl_xor(nS, off);
  }
  float tau = (fs + nU - kf) / fmaxf(nS, 1.f);
  tau = (nS > 0.f) ? tau : tau0;
  float* mo = mu + (size_t)pid*512;
  #pragma unroll
  for (int i = 0; i < 8; ++i) mo[i*64 + lane] = fminf(fmaxf(v[i]-tau, 0.f), 1.f);
}

// -------- hp[b,head,e] = sum_s mu * h --------
__global__ __launch_bounds__(512) void k_hp(
    const float* __restrict__ mu, const float* __restrict__ hf,
    const float* __restrict__ hb, float* __restrict__ hp)
{
  __shared__ float mul[512];
  int pid = blockIdx.x, b = pid >> 2;
  int t = threadIdx.x;
  mul[t] = mu[(size_t)pid*512 + t];
  __syncthreads();
  if (t < ENC_) {
    const float* hsrc = (t < H_) ? (hf + t) : (hb + (t - H_));
    float acc = 0.f;
    for (int s = 0; s < 512; ++s) {
      float m = mul[s];
      if (m != 0.f) acc += m * hsrc[((size_t)b*S_ + s)*H_];
    }
    hp[(size_t)pid*ENC_ + t] = acc;
  }
}

// -------- head --------
__global__ __launch_bounds__(512) void k_head(
    const float* __restrict__ hp, const float* __restrict__ Wv,
    const float* __restrict__ Wout, const float* __restrict__ Wh,
    const float* __restrict__ bh, float* __restrict__ out)
{
  __shared__ float hpl[1600];
  __shared__ float ppl[ENC_];
  __shared__ float ojl[ENC_];
  __shared__ float red[512];
  int b = blockIdx.x, t = threadIdx.x;
  for (int i = t; i < 1600; i += 512) hpl[i] = hp[(size_t)b*1600 + i];
  __syncthreads();
  if (t < ENC_) {
    int head = t / 100;
    float acc = 0.f;
    for (int e = 0; e < ENC_; ++e) acc += hpl[head*ENC_ + e] * Wv[(size_t)e*ENC_ + t];
    ppl[t] = acc;
  }
  __syncthreads();
  if (t < ENC_) {
    float acc = 0.f;
    for (int c = 0; c < ENC_; ++c) acc += ppl[c] * Wout[(size_t)c*ENC_ + t];
    ojl[t] = acc;
  }
  __syncthreads();
  red[t] = (t < ENC_) ? ojl[t]*Wh[t] : 0.f;
  __syncthreads();
  for (int sft = 256; sft; sft >>= 1) {
    if (t < sft) red[t] += red[t+sft];
    __syncthreads();
  }
  if (t == 0) out[b] = 1.f/(1.f + expf(-(red[0] + bh[0])));
}

// -------- z --------
__global__ void k_z(const float* __restrict__ mu, const int* __restrict__ lengths,
                    float* __restrict__ out) {
  int idx = blockIdx.x*256 + threadIdx.x;
  int b = idx >> 9, s = idx & 511;
  float zz = 0.f;
  if (s < lengths[b]) {
    size_t base = (size_t)b*2048 + s;
    zz = 0.25f*(mu[base] + mu[base+512] + mu[base+1024] + mu[base+1536]);
  }
  out[32 + idx] = zz;
}

extern "C" void kernel_launch(void* const* d_in, const int* in_sizes, int n_in,
                              void* d_out, int out_size, void* d_ws, size_t ws_size,
                              hipStream_t stream) {
  const int*   x    = (const int*)d_in[0];
  const void*  mask = d_in[1];
  const float* emb  = (const float*)d_in[2];
  const float* wihf = (const float*)d_in[3];
  const float* whhf = (const float*)d_in[4];
  const float* bf   = (const float*)d_in[5];
  const float* wihb = (const float*)d_in[6];
  const float* whhb = (const float*)d_in[7];
  const float* bb   = (const float*)d_in[8];
  const float* qs   = (const float*)d_in[9];
  const float* Wq   = (const float*)d_in[10];
  const float* Wk   = (const float*)d_in[11];
  const float* Wv   = (const float*)d_in[12];
  const float* Wout = (const float*)d_in[13];
  const float* Wh   = (const float*)d_in[14];
  const float* bh   = (const float*)d_in[15];
  float* out = (float*)d_out;
  float* W = (float*)d_ws;
  int* lengths = (int*)(W + OF_LEN);

  k_lengths<<<32, 64, 0, stream>>>(mask, lengths);
  k_qvec<<<1, 512, 0, stream>>>(qs, Wq, W+OF_QVEC);
  k_wkq<<<7, 256, 0, stream>>>(Wk, W+OF_QVEC, W+OF_WKQ);
  k_gemm_mfma<<<dim3(128, 25), 256, 0, stream>>>(x, emb, wihf, wihb, bf, bb,
                                                 W+OF_XWF, W+OF_XWB);
  k_lstm_v2<<<64, 1024, 0, stream>>>(W+OF_XWF, W+OF_XWB, whhf, whhb,
                                     lengths, W+OF_HF, W+OF_HB);
  k_scores<<<4096, 256, 0, stream>>>(W+OF_HF, W+OF_HB, W+OF_WKQ, lengths, W+OF_THETA);
  k_sparsemap<<<128, 64, 0, stream>>>(W+OF_THETA, lengths, W+OF_MU);
  k_hp<<<128, 512, 0, stream>>>(W+OF_MU, W+OF_HF, W+OF_HB, W+OF_HP);
  k_head<<<32, 512, 0, stream>>>(W+OF_HP, Wv, Wout, Wh, bh, out);
  k_z<<<64, 256, 0, stream>>>(W+OF_MU, lengths, out);
}